// Round 9
// baseline (389.777 us; speedup 1.0000x reference)
//
#include <hip/hip_runtime.h>
#include <hip/hip_bf16.h>
#include <math.h>

#define Nn   1024
#define Cn   192
#define KEPT 256
#define COMP 512
#define UT   128
#define KT   64
#define MARGIN 1e-4f
#define WCAP 1024

typedef __attribute__((ext_vector_type(8))) short short8v;
typedef __attribute__((ext_vector_type(4))) float f32x4;

__device__ __forceinline__ unsigned short f2bf(float f) {
    __bf16 h = (__bf16)f;                        // RNE fptrunc
    return __builtin_bit_cast(unsigned short, h);
}
__device__ __forceinline__ float bf2f(unsigned short u) {
    unsigned v = (unsigned)u << 16;
    return __builtin_bit_cast(float, v);
}
__device__ __forceinline__ unsigned encf(float f) {
    unsigned u = __float_as_uint(f);
    return (u & 0x80000000u) ? ~u : (u | 0x80000000u);
}
__device__ __forceinline__ void split4(float m0, float m1, float m2, float m3,
                                       unsigned long long& hi, unsigned long long& lo) {
    unsigned short h0 = f2bf(m0), h1 = f2bf(m1), h2 = f2bf(m2), h3 = f2bf(m3);
    unsigned short l0 = f2bf(m0 - bf2f(h0));
    unsigned short l1 = f2bf(m1 - bf2f(h1));
    unsigned short l2 = f2bf(m2 - bf2f(h2));
    unsigned short l3 = f2bf(m3 - bf2f(h3));
    hi = (unsigned long long)h0 | ((unsigned long long)h1 << 16)
       | ((unsigned long long)h2 << 32) | ((unsigned long long)h3 << 48);
    lo = (unsigned long long)l0 | ((unsigned long long)l1 << 16)
       | ((unsigned long long)l2 << 32) | ((unsigned long long)l3 << 48);
}

// ======= Fused kernel: one block per b — norm -> bf16x3 MFMA sim -> gather merge =======
__global__ __launch_bounds__(512) void fused_kernel(const float* __restrict__ x,
                                                    float* __restrict__ out) {
    __shared__ __align__(16) unsigned short su_hi[UT * Cn];   // 49152 B (norm scratch overlay)
    __shared__ __align__(16) unsigned short su_lo[UT * Cn];   // 49152 B
    __shared__ __align__(16) unsigned short sk_hi[KT * Cn];   // 24576 B
    __shared__ __align__(16) unsigned short sk_lo[KT * Cn];   // 24576 B
    __shared__ float rl[Cn];
    __shared__ float wl[Cn];
    __shared__ float rowthr[UT];
    __shared__ unsigned long long best[UT];
    __shared__ unsigned short wlist[WCAP];
    __shared__ int nc;
    __shared__ int dstl[COMP];
    __shared__ int cnt[KEPT];
    __shared__ int offp[KEPT];
    __shared__ int fill[KEPT];
    __shared__ unsigned short list[COMP];

    const int b = blockIdx.x;
    const int t = threadIdx.x;
    const float* xb = x + (size_t)b * Nn * Cn;

    // ---------------- Phase 0: norm (sumsq over n per c) ----------------
    // 768 items (16 n-groups x 48 c4); red overlays su_hi.
    float4* red = reinterpret_cast<float4*>(su_hi);
    {
        int ng0 = t / 48, c40 = t % 48;
        float4 s0 = make_float4(0.f, 0.f, 0.f, 0.f);
        #pragma unroll 4
        for (int i = 0; i < 64; ++i) {
            float4 v = *reinterpret_cast<const float4*>(
                xb + (size_t)(ng0 * 64 + i) * Cn + c40 * 4);
            s0.x += v.x * v.x; s0.y += v.y * v.y; s0.z += v.z * v.z; s0.w += v.w * v.w;
        }
        red[t] = s0;
        if (t < 256) {
            int idx = t + 512, ng1 = idx / 48, c41 = idx % 48;
            float4 s1 = make_float4(0.f, 0.f, 0.f, 0.f);
            #pragma unroll 4
            for (int i = 0; i < 64; ++i) {
                float4 v = *reinterpret_cast<const float4*>(
                    xb + (size_t)(ng1 * 64 + i) * Cn + c41 * 4);
                s1.x += v.x * v.x; s1.y += v.y * v.y; s1.z += v.z * v.z; s1.w += v.w * v.w;
            }
            red[idx] = s1;
        }
    }
    __syncthreads();
    if (t < 48) {
        float4 a = make_float4(0.f, 0.f, 0.f, 0.f);
        #pragma unroll
        for (int g = 0; g < 16; ++g) {
            float4 v = red[g * 48 + t];
            a.x += v.x; a.y += v.y; a.z += v.z; a.w += v.w;
        }
        wl[t * 4 + 0] = 1.0f / a.x;  rl[t * 4 + 0] = rsqrtf(a.x);
        wl[t * 4 + 1] = 1.0f / a.y;  rl[t * 4 + 1] = rsqrtf(a.y);
        wl[t * 4 + 2] = 1.0f / a.z;  rl[t * 4 + 2] = rsqrtf(a.z);
        wl[t * 4 + 3] = 1.0f / a.w;  rl[t * 4 + 3] = rsqrtf(a.w);
    }

    // ---------------- Phase 1: sim + argmax per 128-u chunk ----------------
    const int wv   = t >> 6;
    const int ln   = t & 63;
    const int l15  = ln & 15;
    const int hi2  = ln >> 4;
    const int akey = (l15 & 7) << 4;
    const int abase = (wv * 16 + l15) * 384;
    int bbase[4];
    #pragma unroll
    for (int j = 0; j < 4; ++j) bbase[j] = (j * 16 + l15) * 384;

    for (int uc = 0; uc < 4; ++uc) {
        const int u0 = uc * UT;
        __syncthreads();   // red/prior-chunk reads done; safe to reset + restage
        if (t < UT) { rowthr[t] = INFINITY; best[t] = 0ull; }
        if (t == 0) nc = 0;
        __syncthreads();

        // stage su (128 unimp rows) as hi/lo bf16, swizzled (L3-resident reads)
        #pragma unroll
        for (int i = 0; i < 12; ++i) {
            int idx = t + 512 * i;
            int r = idx / 48, c4 = idx % 48;
            float4 v = *reinterpret_cast<const float4*>(
                xb + (size_t)(KEPT + u0 + r) * Cn + c4 * 4);
            unsigned long long hi, lo;
            split4(v.x * rl[c4 * 4 + 0], v.y * rl[c4 * 4 + 1],
                   v.z * rl[c4 * 4 + 2], v.w * rl[c4 * 4 + 3], hi, lo);
            int byte = r * 384 + ((c4 * 8) ^ ((r & 7) << 4));
            *reinterpret_cast<unsigned long long*>(reinterpret_cast<char*>(su_hi) + byte) = hi;
            *reinterpret_cast<unsigned long long*>(reinterpret_cast<char*>(su_lo) + byte) = lo;
        }

        float4 pf[6];
        #pragma unroll
        for (int i = 0; i < 6; ++i) {
            int idx = t + 512 * i;
            int r = idx / 48, c4 = idx % 48;
            pf[i] = *reinterpret_cast<const float4*>(xb + (size_t)r * Cn + c4 * 4);
        }

        f32x4 acc[4][4];
        #pragma unroll
        for (int kt = 0; kt < 4; ++kt)
            #pragma unroll
            for (int j = 0; j < 4; ++j) acc[kt][j] = (f32x4)0.f;

        #pragma unroll
        for (int kt = 0; kt < 4; ++kt) {
            __syncthreads();
            #pragma unroll
            for (int i = 0; i < 6; ++i) {
                int idx = t + 512 * i;
                int r = idx / 48, c4 = idx % 48;
                unsigned long long hi, lo;
                split4(pf[i].x * rl[c4 * 4 + 0], pf[i].y * rl[c4 * 4 + 1],
                       pf[i].z * rl[c4 * 4 + 2], pf[i].w * rl[c4 * 4 + 3], hi, lo);
                int byte = r * 384 + ((c4 * 8) ^ ((r & 7) << 4));
                *reinterpret_cast<unsigned long long*>(reinterpret_cast<char*>(sk_hi) + byte) = hi;
                *reinterpret_cast<unsigned long long*>(reinterpret_cast<char*>(sk_lo) + byte) = lo;
            }
            __syncthreads();
            if (kt < 3) {
                #pragma unroll
                for (int i = 0; i < 6; ++i) {
                    int idx = t + 512 * i;
                    int r = idx / 48, c4 = idx % 48;
                    pf[i] = *reinterpret_cast<const float4*>(
                        xb + (size_t)((kt + 1) * KT + r) * Cn + c4 * 4);
                }
            }

            #pragma unroll
            for (int ks = 0; ks < 6; ++ks) {
                int koff = (ks * 64 + hi2 * 16) ^ akey;
                short8v ah = *reinterpret_cast<const short8v*>(
                    reinterpret_cast<const char*>(su_hi) + abase + koff);
                short8v al = *reinterpret_cast<const short8v*>(
                    reinterpret_cast<const char*>(su_lo) + abase + koff);
                #pragma unroll
                for (int j = 0; j < 4; ++j) {
                    short8v bh = *reinterpret_cast<const short8v*>(
                        reinterpret_cast<const char*>(sk_hi) + bbase[j] + koff);
                    short8v bl = *reinterpret_cast<const short8v*>(
                        reinterpret_cast<const char*>(sk_lo) + bbase[j] + koff);
                    acc[kt][j] = __builtin_amdgcn_mfma_f32_16x16x32_bf16(ah, bh, acc[kt][j], 0, 0, 0);
                    acc[kt][j] = __builtin_amdgcn_mfma_f32_16x16x32_bf16(ah, bl, acc[kt][j], 0, 0, 0);
                    acc[kt][j] = __builtin_amdgcn_mfma_f32_16x16x32_bf16(al, bh, acc[kt][j], 0, 0, 0);
                }
            }
        }

        // ---- top-2 (value, argmax-with-lowest-k, 2nd value) per row ----
        float v1[4], v2[4];
        int   i1[4];
        #pragma unroll
        for (int r = 0; r < 4; ++r) { v1[r] = -INFINITY; v2[r] = -INFINITY; i1[r] = 1; }

        #pragma unroll
        for (int kt = 0; kt < 4; ++kt)
            #pragma unroll
            for (int j = 0; j < 4; ++j) {
                int k = kt * KT + j * 16 + l15;
                #pragma unroll
                for (int r = 0; r < 4; ++r) {
                    float v = acc[kt][j][r];
                    if (k != 0) {
                        if (v > v1[r]) { v2[r] = v1[r]; v1[r] = v; i1[r] = k; }
                        else if (v > v2[r]) v2[r] = v;
                    }
                }
            }

        #pragma unroll
        for (int r = 0; r < 4; ++r) {
            #pragma unroll
            for (int off = 1; off < 16; off <<= 1) {
                float ov1 = __shfl_xor(v1[r], off);
                int   oi1 = __shfl_xor(i1[r], off);
                float ov2 = __shfl_xor(v2[r], off);
                if (ov1 > v1[r] || (ov1 == v1[r] && oi1 < i1[r])) {
                    v2[r] = fmaxf(v1[r], ov2);
                    v1[r] = ov1; i1[r] = oi1;
                } else {
                    v2[r] = fmaxf(v2[r], ov1);
                }
            }
        }

        if (l15 == 0) {
            #pragma unroll
            for (int r = 0; r < 4; ++r) {
                int ur = wv * 16 + hi2 * 4 + r;
                if (v1[r] - v2[r] > MARGIN) dstl[u0 + ur] = i1[r];
                else rowthr[ur] = v1[r] - MARGIN;
            }
        }
        __syncthreads();

        // ---- candidate push for flagged rows ----
        #pragma unroll
        for (int kt = 0; kt < 4; ++kt)
            #pragma unroll
            for (int j = 0; j < 4; ++j) {
                int k = kt * KT + j * 16 + l15;
                if (k == 0) continue;
                #pragma unroll
                for (int r = 0; r < 4; ++r) {
                    int ur = wv * 16 + hi2 * 4 + r;
                    if (acc[kt][j][r] >= rowthr[ur]) {
                        int pos = atomicAdd(&nc, 1);
                        if (pos < WCAP)
                            wlist[pos] = (unsigned short)((ur << 8) | k);
                    }
                }
            }
        __syncthreads();

        // ---- wave-parallel exact fp32 rescue ----
        int n = nc < WCAP ? nc : WCAP;
        for (int ci = wv; ci < n; ci += 8) {
            unsigned item = wlist[ci];
            int ur = item >> 8, k = item & 255;
            const float* xu = xb + (size_t)(KEPT + u0 + ur) * Cn;
            const float* xk = xb + (size_t)k * Cn;
            float p = 0.f;
            if (ln < 48) {
                float4 a  = *reinterpret_cast<const float4*>(xu + ln * 4);
                float4 b4 = *reinterpret_cast<const float4*>(xk + ln * 4);
                p = a.x * b4.x * wl[ln * 4 + 0] + a.y * b4.y * wl[ln * 4 + 1]
                  + a.z * b4.z * wl[ln * 4 + 2] + a.w * b4.w * wl[ln * 4 + 3];
            }
            #pragma unroll
            for (int off = 32; off >= 1; off >>= 1) p += __shfl_xor(p, off);
            if (ln == 0) {
                unsigned long long e = ((unsigned long long)encf(p) << 32)
                                     | (unsigned long long)(0xFFFFFFFFu - (unsigned)k);
                atomicMax(&best[ur], e);
            }
        }
        __syncthreads();

        if (t < UT && rowthr[t] < 3.0e38f) {
            unsigned k = 0xFFFFFFFFu - (unsigned)(best[t] & 0xFFFFFFFFull);
            dstl[u0 + t] = (int)k;
        }
    }
    __syncthreads();

    // ---------------- Phase 2: counting-sort gather merge ----------------
    if (t < KEPT) { cnt[t] = 0; fill[t] = 0; }
    __syncthreads();
    atomicAdd(&cnt[dstl[t]], 1);
    __syncthreads();

    if (t < KEPT) offp[t] = cnt[t];
    __syncthreads();
    #pragma unroll
    for (int d = 1; d < KEPT; d <<= 1) {     // Hillis-Steele inclusive scan
        int v = 0;
        if (t < KEPT && t >= d) v = offp[t - d];
        __syncthreads();
        if (t < KEPT) offp[t] += v;
        __syncthreads();
    }

    {   // scatter u's into per-k sorted list
        int k = dstl[t];
        int pos = offp[k] - cnt[k] + atomicAdd(&fill[k], 1);
        list[pos] = (unsigned short)t;
    }
    __syncthreads();

    float* outb = out + (size_t)b * KEPT * Cn;
    const int qtr = ln >> 4;               // 4 rows per wave, 16 lanes each
    const int cq  = ln & 15;               // c4 = cq, cq+16, cq+32

    for (int pass = 0; pass < 8; ++pass) {
        int k = pass * 32 + wv * 4 + qtr;
        int e = offp[k], c = cnt[k], s0 = e - c;
        const float* xr = xb + (size_t)k * Cn;
        float4 a0 = *reinterpret_cast<const float4*>(xr + cq * 4);
        float4 a1 = *reinterpret_cast<const float4*>(xr + (cq + 16) * 4);
        float4 a2 = *reinterpret_cast<const float4*>(xr + (cq + 32) * 4);
        for (int i = s0; i < e; ++i) {
            const float* xs = xb + (size_t)(KEPT + list[i]) * Cn;
            float4 v0  = *reinterpret_cast<const float4*>(xs + cq * 4);
            float4 v1v = *reinterpret_cast<const float4*>(xs + (cq + 16) * 4);
            float4 v2v = *reinterpret_cast<const float4*>(xs + (cq + 32) * 4);
            a0.x += v0.x;  a0.y += v0.y;  a0.z += v0.z;  a0.w += v0.w;
            a1.x += v1v.x; a1.y += v1v.y; a1.z += v1v.z; a1.w += v1v.w;
            a2.x += v2v.x; a2.y += v2v.y; a2.z += v2v.z; a2.w += v2v.w;
        }
        float rc = 1.0f / ((float)c + 1.0f);
        float* orow = outb + (size_t)k * Cn;
        *reinterpret_cast<float4*>(orow + cq * 4) =
            make_float4(a0.x * rc, a0.y * rc, a0.z * rc, a0.w * rc);
        *reinterpret_cast<float4*>(orow + (cq + 16) * 4) =
            make_float4(a1.x * rc, a1.y * rc, a1.z * rc, a1.w * rc);
        *reinterpret_cast<float4*>(orow + (cq + 32) * 4) =
            make_float4(a2.x * rc, a2.y * rc, a2.z * rc, a2.w * rc);
    }
}

extern "C" void kernel_launch(void* const* d_in, const int* in_sizes, int n_in,
                              void* d_out, int out_size, void* d_ws, size_t ws_size,
                              hipStream_t stream) {
    const float* x = (const float*)d_in[0];
    float* out = (float*)d_out;
    fused_kernel<<<dim3(512), dim3(512), 0, stream>>>(x, out);
}

// Round 10
// 251.466 us; speedup vs baseline: 1.5500x; 1.5500x over previous
//
#include <hip/hip_runtime.h>
#include <hip/hip_bf16.h>
#include <math.h>

#define Nn   1024
#define Cn   192
#define KEPT 256
#define COMP 512
#define UT   128
#define KT   64
#define MARGIN 4e-4f
#define WCAP 1024

typedef __attribute__((ext_vector_type(8))) _Float16 half8v;
typedef __attribute__((ext_vector_type(4))) float f32x4;

__device__ __forceinline__ unsigned encf(float f) {
    unsigned u = __float_as_uint(f);
    return (u & 0x80000000u) ? ~u : (u | 0x80000000u);
}
// pack 4 floats into one u64 of 4 fp16 (RNE)
__device__ __forceinline__ unsigned long long cvt4(float m0, float m1, float m2, float m3) {
    unsigned short h0 = __builtin_bit_cast(unsigned short, (_Float16)m0);
    unsigned short h1 = __builtin_bit_cast(unsigned short, (_Float16)m1);
    unsigned short h2 = __builtin_bit_cast(unsigned short, (_Float16)m2);
    unsigned short h3 = __builtin_bit_cast(unsigned short, (_Float16)m3);
    return (unsigned long long)h0 | ((unsigned long long)h1 << 16)
         | ((unsigned long long)h2 << 32) | ((unsigned long long)h3 << 48);
}

// ---------------- Kernel A: w = 1/sumsq, rsw = rsqrt(sumsq) ----------------
__global__ __launch_bounds__(768) void norm_kernel(const float* __restrict__ x,
                                                   float* __restrict__ w,
                                                   float* __restrict__ rsw) {
    __shared__ float4 red[16][48];
    int b = blockIdx.x, t = threadIdx.x;
    int c4 = t % 48, ng = t / 48;
    const float* xb = x + (size_t)b * Nn * Cn;
    float4 s = make_float4(0.f, 0.f, 0.f, 0.f);
    for (int i = 0; i < 64; ++i) {
        float4 v = *reinterpret_cast<const float4*>(
            xb + (size_t)(ng * 64 + i) * Cn + c4 * 4);
        s.x += v.x * v.x; s.y += v.y * v.y; s.z += v.z * v.z; s.w += v.w * v.w;
    }
    red[ng][c4] = s;
    __syncthreads();
    if (t < 48) {
        float4 a = make_float4(0.f, 0.f, 0.f, 0.f);
        #pragma unroll
        for (int g = 0; g < 16; ++g) {
            float4 v = red[g][t];
            a.x += v.x; a.y += v.y; a.z += v.z; a.w += v.w;
        }
        float4 wv = make_float4(1.0f / a.x, 1.0f / a.y, 1.0f / a.z, 1.0f / a.w);
        float4 rv = make_float4(rsqrtf(a.x), rsqrtf(a.y), rsqrtf(a.z), rsqrtf(a.w));
        *reinterpret_cast<float4*>(w   + (size_t)b * Cn + t * 4) = wv;
        *reinterpret_cast<float4*>(rsw + (size_t)b * Cn + t * 4) = rv;
    }
}

// ------- Kernel B: fp16 MFMA sim + top-2 gap test + wave-parallel exact rescue -------
// 1-D grid 2048, decoded so the 4 u-blocks of each b share an XCD (i%8 round-robin).
// LDS ~78 KB -> 2 blocks/CU.
__global__ __launch_bounds__(512) void sim_kernel(const float* __restrict__ x,
                                                  const float* __restrict__ w,
                                                  const float* __restrict__ rsw,
                                                  int* __restrict__ dst_idx) {
    __shared__ __align__(16) unsigned short su_h[UT * Cn];    // 49152 B
    __shared__ __align__(16) unsigned short sk_h[KT * Cn];    // 24576 B
    __shared__ float rl[Cn];
    __shared__ float wl[Cn];
    __shared__ float rowthr[UT];
    __shared__ unsigned long long best[UT];
    __shared__ unsigned short wlist[WCAP];
    __shared__ int nc;

    const int bi   = blockIdx.x;
    const int xcd  = bi & 7;
    const int slot = bi >> 3;
    const int b    = xcd * 64 + (slot >> 2);
    const int u0   = (slot & 3) * UT;
    const int t    = threadIdx.x;
    const float* xb = x + (size_t)b * Nn * Cn;

    if (t < Cn) { rl[t] = rsw[b * Cn + t]; wl[t] = w[b * Cn + t]; }
    if (t < UT) { rowthr[t] = INFINITY; best[t] = 0ull; }
    if (t == 0) nc = 0;
    __syncthreads();

    // ---- stage su (128 unimp rows) as fp16, swizzled ----
    #pragma unroll
    for (int i = 0; i < 12; ++i) {
        int idx = t + 512 * i;
        int r = idx / 48, c4 = idx % 48;
        float4 v = *reinterpret_cast<const float4*>(
            xb + (size_t)(KEPT + u0 + r) * Cn + c4 * 4);
        unsigned long long h = cvt4(v.x * rl[c4 * 4 + 0], v.y * rl[c4 * 4 + 1],
                                    v.z * rl[c4 * 4 + 2], v.w * rl[c4 * 4 + 3]);
        int byte = r * 384 + ((c4 * 8) ^ ((r & 7) << 4));
        *reinterpret_cast<unsigned long long*>(reinterpret_cast<char*>(su_h) + byte) = h;
    }

    float4 pf[6];
    #pragma unroll
    for (int i = 0; i < 6; ++i) {
        int idx = t + 512 * i;
        int r = idx / 48, c4 = idx % 48;
        pf[i] = *reinterpret_cast<const float4*>(xb + (size_t)r * Cn + c4 * 4);
    }

    const int wv   = t >> 6;
    const int ln   = t & 63;
    const int l15  = ln & 15;
    const int hi2  = ln >> 4;
    const int akey = (l15 & 7) << 4;
    const int abase = (wv * 16 + l15) * 384;
    int bbase[4];
    #pragma unroll
    for (int j = 0; j < 4; ++j) bbase[j] = (j * 16 + l15) * 384;

    f32x4 acc[4][4];
    #pragma unroll
    for (int kt = 0; kt < 4; ++kt)
        #pragma unroll
        for (int j = 0; j < 4; ++j) acc[kt][j] = (f32x4)0.f;

    #pragma unroll
    for (int kt = 0; kt < 4; ++kt) {
        __syncthreads();
        #pragma unroll
        for (int i = 0; i < 6; ++i) {
            int idx = t + 512 * i;
            int r = idx / 48, c4 = idx % 48;
            unsigned long long h = cvt4(pf[i].x * rl[c4 * 4 + 0], pf[i].y * rl[c4 * 4 + 1],
                                        pf[i].z * rl[c4 * 4 + 2], pf[i].w * rl[c4 * 4 + 3]);
            int byte = r * 384 + ((c4 * 8) ^ ((r & 7) << 4));
            *reinterpret_cast<unsigned long long*>(reinterpret_cast<char*>(sk_h) + byte) = h;
        }
        __syncthreads();
        if (kt < 3) {
            #pragma unroll
            for (int i = 0; i < 6; ++i) {
                int idx = t + 512 * i;
                int r = idx / 48, c4 = idx % 48;
                pf[i] = *reinterpret_cast<const float4*>(
                    xb + (size_t)((kt + 1) * KT + r) * Cn + c4 * 4);
            }
        }

        #pragma unroll
        for (int ks = 0; ks < 6; ++ks) {
            int koff = (ks * 64 + hi2 * 16) ^ akey;
            half8v ah = *reinterpret_cast<const half8v*>(
                reinterpret_cast<const char*>(su_h) + abase + koff);
            #pragma unroll
            for (int j = 0; j < 4; ++j) {
                half8v bh = *reinterpret_cast<const half8v*>(
                    reinterpret_cast<const char*>(sk_h) + bbase[j] + koff);
                acc[kt][j] = __builtin_amdgcn_mfma_f32_16x16x32_f16(ah, bh, acc[kt][j], 0, 0, 0);
            }
        }
    }

    // ---- top-2 (value, argmax-with-lowest-k, 2nd value) per row ----
    float v1[4], v2[4];
    int   i1[4];
    #pragma unroll
    for (int r = 0; r < 4; ++r) { v1[r] = -INFINITY; v2[r] = -INFINITY; i1[r] = 1; }

    #pragma unroll
    for (int kt = 0; kt < 4; ++kt)
        #pragma unroll
        for (int j = 0; j < 4; ++j) {
            int k = kt * KT + j * 16 + l15;
            #pragma unroll
            for (int r = 0; r < 4; ++r) {
                float v = acc[kt][j][r];
                if (k != 0) {
                    if (v > v1[r]) { v2[r] = v1[r]; v1[r] = v; i1[r] = k; }
                    else if (v > v2[r]) v2[r] = v;
                }
            }
        }

    #pragma unroll
    for (int r = 0; r < 4; ++r) {
        #pragma unroll
        for (int off = 1; off < 16; off <<= 1) {
            float ov1 = __shfl_xor(v1[r], off);
            int   oi1 = __shfl_xor(i1[r], off);
            float ov2 = __shfl_xor(v2[r], off);
            if (ov1 > v1[r] || (ov1 == v1[r] && oi1 < i1[r])) {
                v2[r] = fmaxf(v1[r], ov2);
                v1[r] = ov1; i1[r] = oi1;
            } else {
                v2[r] = fmaxf(v2[r], ov1);
            }
        }
    }

    if (l15 == 0) {
        #pragma unroll
        for (int r = 0; r < 4; ++r) {
            int ur = wv * 16 + hi2 * 4 + r;
            if (v1[r] - v2[r] > MARGIN) dst_idx[b * COMP + u0 + ur] = i1[r];
            else rowthr[ur] = v1[r] - MARGIN;
        }
    }
    __syncthreads();

    // ---- candidate push for flagged rows ----
    #pragma unroll
    for (int kt = 0; kt < 4; ++kt)
        #pragma unroll
        for (int j = 0; j < 4; ++j) {
            int k = kt * KT + j * 16 + l15;
            if (k == 0) continue;
            #pragma unroll
            for (int r = 0; r < 4; ++r) {
                int ur = wv * 16 + hi2 * 4 + r;
                if (acc[kt][j][r] >= rowthr[ur]) {
                    int pos = atomicAdd(&nc, 1);
                    if (pos < WCAP)
                        wlist[pos] = (unsigned short)((ur << 8) | k);
                }
            }
        }
    __syncthreads();

    // ---- wave-parallel exact fp32 rescue ----
    int n = nc < WCAP ? nc : WCAP;
    for (int ci = wv; ci < n; ci += 8) {
        unsigned item = wlist[ci];
        int ur = item >> 8, k = item & 255;
        const float* xu = xb + (size_t)(KEPT + u0 + ur) * Cn;
        const float* xk = xb + (size_t)k * Cn;
        float p = 0.f;
        if (ln < 48) {
            float4 a  = *reinterpret_cast<const float4*>(xu + ln * 4);
            float4 b4 = *reinterpret_cast<const float4*>(xk + ln * 4);
            p = a.x * b4.x * wl[ln * 4 + 0] + a.y * b4.y * wl[ln * 4 + 1]
              + a.z * b4.z * wl[ln * 4 + 2] + a.w * b4.w * wl[ln * 4 + 3];
        }
        #pragma unroll
        for (int off = 32; off >= 1; off >>= 1) p += __shfl_xor(p, off);
        if (ln == 0) {
            unsigned long long e = ((unsigned long long)encf(p) << 32)
                                 | (unsigned long long)(0xFFFFFFFFu - (unsigned)k);
            atomicMax(&best[ur], e);
        }
    }
    __syncthreads();

    if (t < UT && rowthr[t] < 3.0e38f) {
        unsigned k = 0xFFFFFFFFu - (unsigned)(best[t] & 0xFFFFFFFFull);
        dst_idx[b * COMP + u0 + t] = (int)k;
    }
}

// ------- Kernel C: counting-sort gather merge, 4 rows/wave geometry -------
__global__ __launch_bounds__(512) void merge_kernel(const float* __restrict__ x,
                                                    const int* __restrict__ dst_idx,
                                                    float* __restrict__ out) {
    __shared__ int sidx[COMP];
    __shared__ int cnt[KEPT];
    __shared__ int off[KEPT];     // inclusive prefix sum
    __shared__ int fill[KEPT];
    __shared__ unsigned short list[COMP];

    int b = blockIdx.x, t = threadIdx.x;

    if (t < KEPT) { cnt[t] = 0; fill[t] = 0; }
    sidx[t] = dst_idx[b * COMP + t];
    __syncthreads();
    atomicAdd(&cnt[sidx[t]], 1);
    __syncthreads();

    if (t < KEPT) off[t] = cnt[t];
    __syncthreads();
    #pragma unroll
    for (int d = 1; d < KEPT; d <<= 1) {     // Hillis-Steele inclusive scan
        int v = 0;
        if (t < KEPT && t >= d) v = off[t - d];
        __syncthreads();
        if (t < KEPT) off[t] += v;
        __syncthreads();
    }

    {   // scatter u's into per-k sorted list
        int k = sidx[t];
        int pos = off[k] - cnt[k] + atomicAdd(&fill[k], 1);
        list[pos] = (unsigned short)t;
    }
    __syncthreads();

    const float* xb   = x   + (size_t)b * Nn * Cn;
    float*       outb = out + (size_t)b * KEPT * Cn;
    const int wv  = t >> 6, ln = t & 63;
    const int qtr = ln >> 4;               // 4 rows per wave, 16 lanes each
    const int cq  = ln & 15;               // c4 = cq, cq+16, cq+32

    for (int pass = 0; pass < 8; ++pass) {
        int k = pass * 32 + wv * 4 + qtr;
        int e = off[k], c = cnt[k], s0 = e - c;
        const float* xr = xb + (size_t)k * Cn;
        float4 a0 = *reinterpret_cast<const float4*>(xr + cq * 4);
        float4 a1 = *reinterpret_cast<const float4*>(xr + (cq + 16) * 4);
        float4 a2 = *reinterpret_cast<const float4*>(xr + (cq + 32) * 4);
        for (int i = s0; i < e; ++i) {
            const float* xs = xb + (size_t)(KEPT + list[i]) * Cn;
            float4 v0  = *reinterpret_cast<const float4*>(xs + cq * 4);
            float4 v1v = *reinterpret_cast<const float4*>(xs + (cq + 16) * 4);
            float4 v2v = *reinterpret_cast<const float4*>(xs + (cq + 32) * 4);
            a0.x += v0.x;  a0.y += v0.y;  a0.z += v0.z;  a0.w += v0.w;
            a1.x += v1v.x; a1.y += v1v.y; a1.z += v1v.z; a1.w += v1v.w;
            a2.x += v2v.x; a2.y += v2v.y; a2.z += v2v.z; a2.w += v2v.w;
        }
        float rc = 1.0f / ((float)c + 1.0f);
        float* orow = outb + (size_t)k * Cn;
        *reinterpret_cast<float4*>(orow + cq * 4) =
            make_float4(a0.x * rc, a0.y * rc, a0.z * rc, a0.w * rc);
        *reinterpret_cast<float4*>(orow + (cq + 16) * 4) =
            make_float4(a1.x * rc, a1.y * rc, a1.z * rc, a1.w * rc);
        *reinterpret_cast<float4*>(orow + (cq + 32) * 4) =
            make_float4(a2.x * rc, a2.y * rc, a2.z * rc, a2.w * rc);
    }
}

extern "C" void kernel_launch(void* const* d_in, const int* in_sizes, int n_in,
                              void* d_out, int out_size, void* d_ws, size_t ws_size,
                              hipStream_t stream) {
    const float* x = (const float*)d_in[0];
    float* out = (float*)d_out;

    char* ws = (char*)d_ws;
    float* w       = (float*)ws;                               // 512*192 f32
    float* rsw     = (float*)(ws + (size_t)512 * Cn * 4);      // 512*192 f32
    int*   dst_idx = (int*)  (ws + (size_t)2 * 512 * Cn * 4);  // 512*512 i32

    norm_kernel<<<dim3(512), dim3(768), 0, stream>>>(x, w, rsw);
    sim_kernel<<<dim3(2048), dim3(512), 0, stream>>>(x, w, rsw, dst_idx);
    merge_kernel<<<dim3(512), dim3(512), 0, stream>>>(x, dst_idx, out);
}